// Round 3
// baseline (169.682 us; speedup 1.0000x reference)
//
#include <hip/hip_runtime.h>
#include <hip/hip_bf16.h>

#define NSEQ 256
#define DIM 64
#define NB 128
#define NPAIR 384
#define FINF 1e8f
#define LOG2E 1.4426950408889634f
#define LN2 0.6931471805599453f

using f32x4 = __attribute__((ext_vector_type(4))) float;
using s16x8 = __attribute__((ext_vector_type(8))) short;

__device__ __forceinline__ unsigned short bf16u(float f) {
    __hip_bfloat16 h = __float2bfloat16(f);
    return __builtin_bit_cast(unsigned short, h);
}
__device__ __forceinline__ short bf16s(float f) {
    __hip_bfloat16 h = __float2bfloat16(f);
    return __builtin_bit_cast(short, h);
}

// ---------------------------------------------------------------------------
// Kernel 1: D[p][i][j] = |a_i - b_j|^2, stored DIAGONAL-MAJOR:
//   S[p][(i+j) & 255][i]. One block/pair; waves own 64-col blocks; 64-row
//   stripes transposed through swizzled LDS (reusing b_lds) for coalesced
//   128B-run writes per S-row. LDS 66KB -> 2 blocks/CU.
// ---------------------------------------------------------------------------
__global__ __launch_bounds__(256, 2)
void dist_kernel(const float* __restrict__ X, const float* __restrict__ Y,
                 unsigned short* __restrict__ S) {
    __shared__ __align__(16) short a_lds[NSEQ * DIM];
    __shared__ __align__(16) short b_lds[NSEQ * DIM];  // reused as sbuf later
    __shared__ float a2[NSEQ];
    __shared__ float b2[NSEQ];
    unsigned short* sbuf = reinterpret_cast<unsigned short*>(b_lds);

    const int p = blockIdx.x;
    const int b = p & (NB - 1);
    const int g = p >> 7;  // 0: (x,y)  1: (x,x)  2: (y,y)
    const float* Arow = (g == 2 ? Y : X) + (size_t)b * NSEQ * DIM;
    const float* Brow = (g == 1 ? X : Y) + (size_t)b * NSEQ * DIM;

    const int t = threadIdx.x;
    {
        const float4* av = reinterpret_cast<const float4*>(Arow) + t * (DIM / 4);
        const float4* bv = reinterpret_cast<const float4*>(Brow) + t * (DIM / 4);
        float sa = 0.f, sb = 0.f;
#pragma unroll
        for (int q = 0; q < 8; ++q) {
            float4 a0 = av[2 * q], a1 = av[2 * q + 1];
            float4 b0 = bv[2 * q], b1 = bv[2 * q + 1];
            sa += a0.x * a0.x + a0.y * a0.y + a0.z * a0.z + a0.w * a0.w
                + a1.x * a1.x + a1.y * a1.y + a1.z * a1.z + a1.w * a1.w;
            sb += b0.x * b0.x + b0.y * b0.y + b0.z * b0.z + b0.w * b0.w
                + b1.x * b1.x + b1.y * b1.y + b1.z * b1.z + b1.w * b1.w;
            s16x8 pa = { bf16s(a0.x), bf16s(a0.y), bf16s(a0.z), bf16s(a0.w),
                         bf16s(a1.x), bf16s(a1.y), bf16s(a1.z), bf16s(a1.w) };
            s16x8 pb = { bf16s(b0.x), bf16s(b0.y), bf16s(b0.z), bf16s(b0.w),
                         bf16s(b1.x), bf16s(b1.y), bf16s(b1.z), bf16s(b1.w) };
            const int off = t * DIM + ((q ^ (t & 7)) << 3);
            *reinterpret_cast<s16x8*>(&a_lds[off]) = pa;
            *reinterpret_cast<s16x8*>(&b_lds[off]) = pb;
        }
        a2[t] = sa;
        b2[t] = sb;
    }
    __syncthreads();

    const int wave = t >> 6;
    const int lane = t & 63;
    const int lrow = lane & 15;
    const int lk   = lane >> 4;  // 0..3

    // B fragments: wave owns cols [64*wave, 64*wave+64)
    s16x8 bfr[4][2];
    float bn[4];
#pragma unroll
    for (int ct = 0; ct < 4; ++ct) {
        const int c = 64 * wave + ct * 16 + lrow;
#pragma unroll
        for (int kk = 0; kk < 2; ++kk) {
            const int kb = kk * 4 + lk;
            bfr[ct][kk] = *reinterpret_cast<const s16x8*>(
                &b_lds[c * DIM + ((kb ^ (c & 7)) << 3)]);
        }
        bn[ct] = b2[c];
    }
    __syncthreads();  // all waves done with b_lds; it becomes sbuf now

    const size_t pbase = (size_t)p * (NSEQ * NSEQ);
#pragma unroll 1
    for (int stripe = 0; stripe < 4; ++stripe) {
        const int r0 = stripe * 64;
        s16x8 afr[4][2];
#pragma unroll
        for (int rt = 0; rt < 4; ++rt) {
            const int r = r0 + rt * 16 + lrow;
#pragma unroll
            for (int kk = 0; kk < 2; ++kk) {
                const int kb = kk * 4 + lk;
                afr[rt][kk] = *reinterpret_cast<const s16x8*>(
                    &a_lds[r * DIM + ((kb ^ (r & 7)) << 3)]);
            }
        }
#pragma unroll
        for (int ct = 0; ct < 4; ++ct) {
            const int c = 64 * wave + ct * 16 + lrow;
#pragma unroll
            for (int rt = 0; rt < 4; ++rt) {
                f32x4 acc = {0.f, 0.f, 0.f, 0.f};
                acc = __builtin_amdgcn_mfma_f32_16x16x32_bf16(afr[rt][0], bfr[ct][0], acc, 0, 0, 0);
                acc = __builtin_amdgcn_mfma_f32_16x16x32_bf16(afr[rt][1], bfr[ct][1], acc, 0, 0, 0);
                // C/D: col = lane&15 (=c), row = lk*4 + jv  [m89-verified]
#pragma unroll
                for (int jv = 0; jv < 4; ++jv) {
                    const int rloc = rt * 16 + lk * 4 + jv;
                    const float dist = a2[r0 + rloc] + bn[ct] - 2.f * acc[jv];
                    sbuf[rloc * NSEQ + (c ^ (((rloc >> 2) & 3) << 4))] = bf16u(dist);
                }
            }
        }
        __syncthreads();
        // writeout: per s-row, this stripe contributes S[s][r0..r0+64) (128B)
        const int sl = lane >> 4;
        const int q  = lane & 15;
#pragma unroll
        for (int gg = 0; gg < 16; ++gg) {
            const int s = 64 * wave + gg * 4 + sl;
            const int il0 = 4 * q;
            const int swz = ((q & 3) << 4);
            const int j0 = (s - (r0 + il0 + 0)) & 255;
            const int j1 = (s - (r0 + il0 + 1)) & 255;
            const int j2 = (s - (r0 + il0 + 2)) & 255;
            const int j3 = (s - (r0 + il0 + 3)) & 255;
            unsigned int e0 = sbuf[(il0 + 0) * NSEQ + (j0 ^ swz)];
            unsigned int e1 = sbuf[(il0 + 1) * NSEQ + (j1 ^ swz)];
            unsigned int e2 = sbuf[(il0 + 2) * NSEQ + (j2 ^ swz)];
            unsigned int e3 = sbuf[(il0 + 3) * NSEQ + (j3 ^ swz)];
            uint2 w;
            w.x = e0 | (e1 << 16);
            w.y = e2 | (e3 << 16);
            *reinterpret_cast<uint2*>(&S[pbase + (size_t)s * NSEQ + r0 + 4 * q]) = w;
        }
        __syncthreads();
    }
}

// ---------------------------------------------------------------------------
// Kernel 2: soft-DTW DP. One wave/pair, 4 rows/lane, state in VGPRs.
// D diagonals staged global->LDS via global_load_lds into a 4-slot x 8-diag
// ring (16KB), prefetched 3 chunks (24 diagonals) ahead, gated by counted
// s_waitcnt vmcnt(12). No barriers (single wave). Softmin in base-2 domain
// with min3/med3/max3: e = 1 + 2^(m-med) + 2^(m-max)  (2 exp2 + 1 log/cell).
// ---------------------------------------------------------------------------
__global__ __launch_bounds__(64, 1)
void dtw_kernel(const unsigned short* __restrict__ S, float* __restrict__ rout) {
    __shared__ __align__(16) unsigned short sd[32 * NSEQ];  // 16 KB ring
    const int p = blockIdx.x;
    const int L = threadIdx.x;
    const unsigned short* Sp = S + (size_t)p * (NSEQ * NSEQ);
    const int i0 = 4 * L;

    auto stage = [&](int cc) {  // stage chunk cc (diags 8cc..8cc+7) -> slot cc&3
        const int row = (8 * cc) & 255;
        const unsigned short* gsrc = Sp + row * NSEQ + L * 8;
        unsigned short* lbase = &sd[(cc & 3) * 2048];
#pragma unroll
        for (int i = 0; i < 4; ++i) {
            __builtin_amdgcn_global_load_lds(
                (const __attribute__((address_space(1))) void*)(gsrc + i * 512),
                (__attribute__((address_space(3))) void*)(lbase + i * 512),
                16, 0, 0);
        }
    };

    float r1[4], r2[4];
#pragma unroll
    for (int k = 0; k < 4; ++k) { r1[k] = FINF; r2[k] = FINF; }

    auto step = [&](int d) {
        const uint2 w = *reinterpret_cast<const uint2*>(&sd[((d & 31) << 8) + i0]);
        float dv[4];
        dv[0] = __builtin_bit_cast(float, w.x << 16);
        dv[1] = __builtin_bit_cast(float, w.x & 0xffff0000u);
        dv[2] = __builtin_bit_cast(float, w.y << 16);
        dv[3] = __builtin_bit_cast(float, w.y & 0xffff0000u);
        float up1 = __shfl_up(r1[3], 1);
        float up2 = __shfl_up(r2[3], 1);
        if (L == 0) { up1 = FINF; up2 = (d == 0) ? 0.f : FINF; }
        const int tj = d - i0;
        float rn[4];
#pragma unroll
        for (int k = 0; k < 4; ++k) {
            const float a = (k == 0) ? up2 : r2[k - 1];   // R'[i-1][j-1]
            const float bb = (k == 0) ? up1 : r1[k - 1];  // R'[i-1][j]
            const float c = r1[k];                         // R'[i][j-1]
            const float m   = fminf(fminf(a, bb), c);
            const float med = __builtin_amdgcn_fmed3f(a, bb, c);
            const float M   = fmaxf(fmaxf(a, bb), c);
            const float e = 1.0f + __builtin_amdgcn_exp2f(m - med)
                                 + __builtin_amdgcn_exp2f(m - M);
            const float sm = m - __builtin_amdgcn_logf(e);  // log2
            rn[k] = ((unsigned)(tj - k) < 256u) ? __builtin_fmaf(dv[k], LOG2E, sm)
                                                : FINF;
        }
#pragma unroll
        for (int k = 0; k < 4; ++k) { r2[k] = r1[k]; r1[k] = rn[k]; }
    };

    stage(0); stage(1); stage(2);

#pragma unroll 1
    for (int c = 0; c < 61; ++c) {
        stage(c + 3);
        asm volatile("s_waitcnt vmcnt(12)" ::: "memory");
        __builtin_amdgcn_sched_barrier(0);
        const int d0 = 8 * c;
#pragma unroll
        for (int u = 0; u < 8; ++u) step(d0 + u);
    }
    asm volatile("s_waitcnt vmcnt(0)" ::: "memory");
    __builtin_amdgcn_sched_barrier(0);
#pragma unroll
    for (int d = 488; d < 511; ++d) step(d);

    if (L == 63) rout[p] = r1[3] * LN2;  // unscale from base-2 domain
}

// ---------------------------------------------------------------------------
// Kernel 3: loss = mean_b( r[b] - 0.5*(r[b+128] + r[b+256]) ) + 1e-5
// ---------------------------------------------------------------------------
__global__ void reduce_kernel(const float* __restrict__ rr, float* __restrict__ out) {
    const int t = threadIdx.x;  // 128 threads
    float v = rr[t] - 0.5f * (rr[t + 128] + rr[t + 256]);
#pragma unroll
    for (int o = 32; o > 0; o >>= 1) v += __shfl_down(v, o);
    __shared__ float sred[2];
    if ((t & 63) == 0) sred[t >> 6] = v;
    __syncthreads();
    if (t == 0) out[0] = (sred[0] + sred[1]) * (1.f / 128.f) + 1e-5f;
}

extern "C" void kernel_launch(void* const* d_in, const int* in_sizes, int n_in,
                              void* d_out, int out_size, void* d_ws, size_t ws_size,
                              hipStream_t stream) {
    const float* X = (const float*)d_in[0];  // outputs (128,256,64) f32
    const float* Y = (const float*)d_in[1];  // targets (128,256,64) f32
    float* out = (float*)d_out;

    const size_t dbytes = (size_t)NPAIR * NSEQ * NSEQ * sizeof(unsigned short);
    const size_t need = dbytes + (size_t)NPAIR * sizeof(float);
    if (ws_size < need) {
        hipMemsetAsync(d_out, 0x7f, sizeof(float), stream);  // sentinel
        return;
    }
    unsigned short* Sws = (unsigned short*)d_ws;
    float* rws = (float*)((char*)d_ws + dbytes);

    dist_kernel<<<NPAIR, 256, 0, stream>>>(X, Y, Sws);
    dtw_kernel<<<NPAIR, 64, 0, stream>>>(Sws, rws);
    reduce_kernel<<<1, 128, 0, stream>>>(rws, out);
}

// Round 6
// 115.818 us; speedup vs baseline: 1.4651x; 1.4651x over previous
//
#include <hip/hip_runtime.h>
#include <hip/hip_bf16.h>

#define NSEQ 256
#define DIM 64
#define NB 128
#define NPAIR 384
#define FINF 1e8f
#define LOG2E 1.4426950408889634f
#define LN2 0.6931471805599453f

using f32x4 = __attribute__((ext_vector_type(4))) float;
using s16x8 = __attribute__((ext_vector_type(8))) short;

__device__ __forceinline__ unsigned short bf16u(float f) {
    __hip_bfloat16 h = __float2bfloat16(f);
    return __builtin_bit_cast(unsigned short, h);
}
__device__ __forceinline__ short bf16s(float f) {
    __hip_bfloat16 h = __float2bfloat16(f);
    return __builtin_bit_cast(short, h);
}

// ---------------------------------------------------------------------------
// Kernel 1: D[p][i][j] = |a_i - b_j|^2, stored DIAGONAL-MAJOR:
//   S[p][(i+j) & 255][i]  (diagonals d and d+256 pack one 256-row exactly).
// (unchanged from round 3 — verified passing)
// ---------------------------------------------------------------------------
__global__ __launch_bounds__(256, 2)
void dist_kernel(const float* __restrict__ X, const float* __restrict__ Y,
                 unsigned short* __restrict__ S) {
    __shared__ __align__(16) short a_lds[NSEQ * DIM];
    __shared__ __align__(16) short b_lds[NSEQ * DIM];  // reused as sbuf later
    __shared__ float a2[NSEQ];
    __shared__ float b2[NSEQ];
    unsigned short* sbuf = reinterpret_cast<unsigned short*>(b_lds);

    const int p = blockIdx.x;
    const int b = p & (NB - 1);
    const int g = p >> 7;  // 0: (x,y)  1: (x,x)  2: (y,y)
    const float* Arow = (g == 2 ? Y : X) + (size_t)b * NSEQ * DIM;
    const float* Brow = (g == 1 ? X : Y) + (size_t)b * NSEQ * DIM;

    const int t = threadIdx.x;
    {
        const float4* av = reinterpret_cast<const float4*>(Arow) + t * (DIM / 4);
        const float4* bv = reinterpret_cast<const float4*>(Brow) + t * (DIM / 4);
        float sa = 0.f, sb = 0.f;
#pragma unroll
        for (int q = 0; q < 8; ++q) {
            float4 a0 = av[2 * q], a1 = av[2 * q + 1];
            float4 b0 = bv[2 * q], b1 = bv[2 * q + 1];
            sa += a0.x * a0.x + a0.y * a0.y + a0.z * a0.z + a0.w * a0.w
                + a1.x * a1.x + a1.y * a1.y + a1.z * a1.z + a1.w * a1.w;
            sb += b0.x * b0.x + b0.y * b0.y + b0.z * b0.z + b0.w * b0.w
                + b1.x * b1.x + b1.y * b1.y + b1.z * b1.z + b1.w * b1.w;
            s16x8 pa = { bf16s(a0.x), bf16s(a0.y), bf16s(a0.z), bf16s(a0.w),
                         bf16s(a1.x), bf16s(a1.y), bf16s(a1.z), bf16s(a1.w) };
            s16x8 pb = { bf16s(b0.x), bf16s(b0.y), bf16s(b0.z), bf16s(b0.w),
                         bf16s(b1.x), bf16s(b1.y), bf16s(b1.z), bf16s(b1.w) };
            const int off = t * DIM + ((q ^ (t & 7)) << 3);
            *reinterpret_cast<s16x8*>(&a_lds[off]) = pa;
            *reinterpret_cast<s16x8*>(&b_lds[off]) = pb;
        }
        a2[t] = sa;
        b2[t] = sb;
    }
    __syncthreads();

    const int wave = t >> 6;
    const int lane = t & 63;
    const int lrow = lane & 15;
    const int lk   = lane >> 4;

    s16x8 bfr[4][2];
    float bn[4];
#pragma unroll
    for (int ct = 0; ct < 4; ++ct) {
        const int c = 64 * wave + ct * 16 + lrow;
#pragma unroll
        for (int kk = 0; kk < 2; ++kk) {
            const int kb = kk * 4 + lk;
            bfr[ct][kk] = *reinterpret_cast<const s16x8*>(
                &b_lds[c * DIM + ((kb ^ (c & 7)) << 3)]);
        }
        bn[ct] = b2[c];
    }
    __syncthreads();  // all waves done with b_lds; it becomes sbuf now

    const size_t pbase = (size_t)p * (NSEQ * NSEQ);
#pragma unroll 1
    for (int stripe = 0; stripe < 4; ++stripe) {
        const int r0 = stripe * 64;
        s16x8 afr[4][2];
#pragma unroll
        for (int rt = 0; rt < 4; ++rt) {
            const int r = r0 + rt * 16 + lrow;
#pragma unroll
            for (int kk = 0; kk < 2; ++kk) {
                const int kb = kk * 4 + lk;
                afr[rt][kk] = *reinterpret_cast<const s16x8*>(
                    &a_lds[r * DIM + ((kb ^ (r & 7)) << 3)]);
            }
        }
#pragma unroll
        for (int ct = 0; ct < 4; ++ct) {
            const int c = 64 * wave + ct * 16 + lrow;
#pragma unroll
            for (int rt = 0; rt < 4; ++rt) {
                f32x4 acc = {0.f, 0.f, 0.f, 0.f};
                acc = __builtin_amdgcn_mfma_f32_16x16x32_bf16(afr[rt][0], bfr[ct][0], acc, 0, 0, 0);
                acc = __builtin_amdgcn_mfma_f32_16x16x32_bf16(afr[rt][1], bfr[ct][1], acc, 0, 0, 0);
#pragma unroll
                for (int jv = 0; jv < 4; ++jv) {
                    const int rloc = rt * 16 + lk * 4 + jv;
                    const float dist = a2[r0 + rloc] + bn[ct] - 2.f * acc[jv];
                    sbuf[rloc * NSEQ + (c ^ (((rloc >> 2) & 3) << 4))] = bf16u(dist);
                }
            }
        }
        __syncthreads();
        const int sl = lane >> 4;
        const int q  = lane & 15;
#pragma unroll
        for (int gg = 0; gg < 16; ++gg) {
            const int s = 64 * wave + gg * 4 + sl;
            const int il0 = 4 * q;
            const int swz = ((q & 3) << 4);
            const int j0 = (s - (r0 + il0 + 0)) & 255;
            const int j1 = (s - (r0 + il0 + 1)) & 255;
            const int j2 = (s - (r0 + il0 + 2)) & 255;
            const int j3 = (s - (r0 + il0 + 3)) & 255;
            unsigned int e0 = sbuf[(il0 + 0) * NSEQ + (j0 ^ swz)];
            unsigned int e1 = sbuf[(il0 + 1) * NSEQ + (j1 ^ swz)];
            unsigned int e2 = sbuf[(il0 + 2) * NSEQ + (j2 ^ swz)];
            unsigned int e3 = sbuf[(il0 + 3) * NSEQ + (j3 ^ swz)];
            uint2 w;
            w.x = e0 | (e1 << 16);
            w.y = e2 | (e3 << 16);
            *reinterpret_cast<uint2*>(&S[pbase + (size_t)s * NSEQ + r0 + 4 * q]) = w;
        }
        __syncthreads();
    }
}

// ---------------------------------------------------------------------------
// Kernel 2: soft-DTW DP, log-domain (base-2), EXACT math of round 2 but:
//  - one DPP wave_shr:1 per step replaces both ds_bpermute shuffles
//    (old-operand = 1e8 gives the lane-0 INF boundary for free;
//     up2_next = up1_cur supplies the second shifted diagonal)
//  - no validity masks: out-of-band cells ride a ~1e8 rail (invalid dv
//    reads are wrapped positive D >= ~60 -> spurious softmin terms
//    weigh <= 2^-86; entry/exit contamination is provably harmless)
//  - med3-form softmin: e = 1 + 2^(m-med) + 2^(m-max)  (exact identity)
//  - D staged via global_load_lds ring (4 slots x 8 diagonals, vmcnt(8))
// ---------------------------------------------------------------------------
__global__ __launch_bounds__(64, 1)
void dtw_kernel(const unsigned short* __restrict__ S, float* __restrict__ rout) {
    __shared__ __align__(16) unsigned short sd[32 * NSEQ];  // 16 KB ring
    const int p = blockIdx.x;
    const int L = threadIdx.x;
    const unsigned short* Sp = S + (size_t)p * (NSEQ * NSEQ);
    const int i0 = 4 * L;

    auto stage = [&](int cc) {  // rows (8cc..8cc+7)&255 -> slot cc&3
        const int row = (8 * cc) & 255;
        const unsigned short* gsrc = Sp + row * NSEQ + L * 8;
        unsigned short* lbase = &sd[(cc & 3) * 2048];
#pragma unroll
        for (int i = 0; i < 4; ++i) {
            __builtin_amdgcn_global_load_lds(
                (const __attribute__((address_space(1))) void*)(gsrc + i * 512),
                (__attribute__((address_space(3))) void*)(lbase + i * 512),
                16, 0, 0);
        }
    };

    float r1[4], r2[4];
#pragma unroll
    for (int k = 0; k < 4; ++k) { r1[k] = FINF; r2[k] = FINF; }
    float up1 = FINF;                   // shift(r1[3]) for current step
    float up2 = (L == 0) ? 0.f : FINF;  // shift(r2[3]); lane0 row0: R[-1][-1]=0

    const int finf_bits = __builtin_bit_cast(int, FINF);

    auto step = [&](int d) {
        const uint2 w = *reinterpret_cast<const uint2*>(&sd[((d & 31) << 8) + i0]);
        float dv[4];
        dv[0] = __builtin_bit_cast(float, w.x << 16);
        dv[1] = __builtin_bit_cast(float, w.x & 0xffff0000u);
        dv[2] = __builtin_bit_cast(float, w.y << 16);
        dv[3] = __builtin_bit_cast(float, w.y & 0xffff0000u);
        float rn[4];
#pragma unroll
        for (int k = 0; k < 4; ++k) {
            const float a = (k == 0) ? up2 : r2[k - 1];   // R'[i-1][j-1]
            const float bb = (k == 0) ? up1 : r1[k - 1];  // R'[i-1][j]
            const float c = r1[k];                         // R'[i][j-1]
            const float m   = fminf(fminf(a, bb), c);
            const float med = __builtin_amdgcn_fmed3f(a, bb, c);
            const float M   = fmaxf(fmaxf(a, bb), c);
            const float e = 1.0f + __builtin_amdgcn_exp2f(m - med)
                                 + __builtin_amdgcn_exp2f(m - M);
            const float sm = m - __builtin_amdgcn_logf(e);  // v_log_f32 = log2
            rn[k] = __builtin_fmaf(dv[k], LOG2E, sm);
        }
        // boundary: lane L gets lane L-1's rn[3]; lane 0 keeps old = FINF
        const float up1n = __builtin_bit_cast(float,
            __builtin_amdgcn_update_dpp(finf_bits,
                __builtin_bit_cast(int, rn[3]),
                0x138 /*wave_shr:1*/, 0xF, 0xF, false));
        up2 = up1;
        up1 = up1n;
#pragma unroll
        for (int k = 0; k < 4; ++k) { r2[k] = r1[k]; r1[k] = rn[k]; }
    };

    stage(0); stage(1); stage(2);
    asm volatile("s_waitcnt vmcnt(8)" ::: "memory");  // chunk 0 landed

#pragma unroll 1
    for (int c = 0; c < 63; ++c) {
        stage(c + 3);  // c>=61 wraps: stages unread data, keeps waits uniform
        asm volatile("s_waitcnt vmcnt(8)" ::: "memory");  // chunk c+1 landed
        const int d0 = 8 * c;
#pragma unroll
        for (int u = 0; u < 8; ++u) step(d0 + u);
    }
#pragma unroll
    for (int u = 0; u < 7; ++u) step(504 + u);  // chunk 63 (landed at c=62)

    if (L == 63) rout[p] = r1[3] * LN2;  // base-2 -> nats
}

// ---------------------------------------------------------------------------
// Kernel 3: loss = mean_b( r[b] - 0.5*(r[b+128] + r[b+256]) ) + 1e-5
// ---------------------------------------------------------------------------
__global__ void reduce_kernel(const float* __restrict__ rr, float* __restrict__ out) {
    const int t = threadIdx.x;  // 128 threads
    float v = rr[t] - 0.5f * (rr[t + 128] + rr[t + 256]);
#pragma unroll
    for (int o = 32; o > 0; o >>= 1) v += __shfl_down(v, o);
    __shared__ float sred[2];
    if ((t & 63) == 0) sred[t >> 6] = v;
    __syncthreads();
    if (t == 0) out[0] = (sred[0] + sred[1]) * (1.f / 128.f) + 1e-5f;
}

extern "C" void kernel_launch(void* const* d_in, const int* in_sizes, int n_in,
                              void* d_out, int out_size, void* d_ws, size_t ws_size,
                              hipStream_t stream) {
    const float* X = (const float*)d_in[0];  // outputs (128,256,64) f32
    const float* Y = (const float*)d_in[1];  // targets (128,256,64) f32
    float* out = (float*)d_out;

    const size_t dbytes = (size_t)NPAIR * NSEQ * NSEQ * sizeof(unsigned short);
    const size_t need = dbytes + (size_t)NPAIR * sizeof(float);
    if (ws_size < need) {
        hipMemsetAsync(d_out, 0x7f, sizeof(float), stream);  // sentinel
        return;
    }
    unsigned short* Sws = (unsigned short*)d_ws;
    float* rws = (float*)((char*)d_ws + dbytes);

    dist_kernel<<<NPAIR, 256, 0, stream>>>(X, Y, Sws);
    dtw_kernel<<<NPAIR, 64, 0, stream>>>(Sws, rws);
    reduce_kernel<<<1, 128, 0, stream>>>(rws, out);
}